// Round 6
// baseline (188.992 us; speedup 1.0000x reference)
//
#include <hip/hip_runtime.h>
#include <hip/hip_cooperative_groups.h>
#include <math.h>

// SEFusion: x [N=25, C=256, H=48, W=176] f32. V4 = CHW/4 = 540,672 float4.
#define CHW     2162688
#define V4      540672
#define NTOK    25
#define NBLK    1024
#define CHUNK1  13200            // (NTOK*V4)/NBLK  -- phase-1 float4 per block
#define CHUNK3  528              // V4/NBLK         -- phase-3 float4 per block
#define MAXCAV  5
#define NBATCH  8

// fallback-path constants (R4 kernels, known-good)
#define BPT      64
#define V4_BLK   8448
#define ITERS    33

namespace cg = cooperative_groups;
typedef float f32x4 __attribute__((ext_vector_type(4)));

__device__ __forceinline__ void relu_store(float ax, float ay, float az, float aw,
                                           float4* __restrict__ out, int o) {
    f32x4 acc;
    acc.x = fmaxf(ax, 0.0f);
    acc.y = fmaxf(ay, 0.0f);
    acc.z = fmaxf(az, 0.0f);
    acc.w = fmaxf(aw, 0.0f);
    __builtin_nontemporal_store(acc, (f32x4*)(out + o));
}

template <int LEN>
__device__ __forceinline__ void apply_idx(const float4* __restrict__ x,
                                          const float* c, float bias,
                                          int start, int obase, int idx,
                                          float4* __restrict__ out) {
    float ax = bias, ay = bias, az = bias, aw = bias;
    #pragma unroll
    for (int m = 0; m < LEN; ++m) {
        float4 v = x[(start + m) * V4 + idx];
        ax += c[m] * v.x;
        ay += c[m] * v.y;
        az += c[m] * v.z;
        aw += c[m] * v.w;
    }
    relu_store(ax, ay, az, aw, out, obase + idx);
}

// ======================= fused cooperative kernel ==========================
template <int LEN>
__device__ __forceinline__ void apply_chunk(const float4* __restrict__ x,
                                            const float* c, float bias,
                                            int start, int obase, int base3,
                                            int tid, float4* __restrict__ out) {
    apply_idx<LEN>(x, c, bias, start, obase, base3 + tid, out);
    apply_idx<LEN>(x, c, bias, start, obase, base3 + 256 + tid, out);
    if (tid < CHUNK3 - 512)
        apply_idx<LEN>(x, c, bias, start, obase, base3 + 512 + tid, out);
}

__global__ __launch_bounds__(256, 4) void k_fused(
    const float4* __restrict__ x,
    const int*   __restrict__ record_len,
    const float* __restrict__ W1,
    const float* __restrict__ W2,
    const float* __restrict__ conv_w,
    const float* __restrict__ conv_b,
    float4* __restrict__ out,
    float* __restrict__ ps,       // [2*NBLK] bucket partial sums
    float* __restrict__ pm)       // [2*NBLK] bucket partial maxes
{
    const int tid  = threadIdx.x;
    const int bid  = blockIdx.x;
    const int lane = tid & 63;
    const int wave = tid >> 6;

    // ---------- phase 1: flat-chunk reduce, 2 token buckets per block -----
    const int base  = bid * CHUNK1;
    const int t0    = base / V4;
    const int split = min((t0 + 1) * V4 - base, CHUNK1);

    float s0 = 0.f, s1 = 0.f, m0 = -INFINITY, m1 = -INFINITY;
    #pragma unroll 2
    for (int li = tid; li < CHUNK1; li += 256) {
        float4 v = x[base + li];
        float vs = (v.x + v.y) + (v.z + v.w);
        float vm = fmaxf(fmaxf(v.x, v.y), fmaxf(v.z, v.w));
        if (li < split) { s0 += vs; m0 = fmaxf(m0, vm); }
        else            { s1 += vs; m1 = fmaxf(m1, vm); }
    }
    #pragma unroll
    for (int off = 32; off > 0; off >>= 1) {
        s0 += __shfl_xor(s0, off, 64);
        s1 += __shfl_xor(s1, off, 64);
        m0 = fmaxf(m0, __shfl_xor(m0, off, 64));
        m1 = fmaxf(m1, __shfl_xor(m1, off, 64));
    }
    __shared__ float rs0[4], rs1[4], rm0[4], rm1[4];
    if (lane == 0) { rs0[wave] = s0; rs1[wave] = s1; rm0[wave] = m0; rm1[wave] = m1; }
    __syncthreads();
    if (tid == 0) {
        ps[2 * bid]     = rs0[0] + rs0[1] + rs0[2] + rs0[3];
        ps[2 * bid + 1] = rs1[0] + rs1[1] + rs1[2] + rs1[3];
        pm[2 * bid]     = fmaxf(fmaxf(rm0[0], rm0[1]), fmaxf(rm0[2], rm0[3]));
        pm[2 * bid + 1] = fmaxf(fmaxf(rm1[0], rm1[1]), fmaxf(rm1[2], rm1[3]));
    }

    cg::this_grid().sync();

    // ---------- phase 2: replicated gate (partials are L2-resident) -------
    __shared__ float tsum[NTOK], tmax[NTOK];
    __shared__ float scoef[NBATCH][MAXCAV];
    __shared__ int   sstart[NBATCH], slen[NBATCH];
    __shared__ float sbias;

    for (int t = wave; t < NTOK; t += 4) {
        const int b_lo = (t == 0) ? 0 : ((t - 1) * V4 + CHUNK1 - 1) / CHUNK1;
        const int b_hi = min(NBLK - 1, ((t + 1) * V4 + CHUNK1 - 1) / CHUNK1 - 1);
        float s = 0.f, m = -INFINITY;
        for (int b = b_lo + lane; b <= b_hi; b += 64) {
            const int tb = (b * CHUNK1) / V4;
            if (tb == t)     { s += ps[2 * b];     m = fmaxf(m, pm[2 * b]); }
            if (tb == t - 1) { s += ps[2 * b + 1]; m = fmaxf(m, pm[2 * b + 1]); }
        }
        #pragma unroll
        for (int off = 32; off > 0; off >>= 1) {
            s += __shfl_xor(s, off, 64);
            m = fmaxf(m, __shfl_xor(m, off, 64));
        }
        if (lane == 0) { tsum[t] = s; tmax[t] = m; }
    }
    __syncthreads();

    if (tid < NBATCH) {
        const int b = tid;
        int start = 0;
        for (int i = 0; i < b; ++i) start += record_len[i];
        const int len = record_len[b];
        sstart[b] = start;
        slen[b]   = len;

        float xsq[2 * MAXCAV];
        #pragma unroll
        for (int m = 0; m < MAXCAV; ++m) {
            const bool valid = m < len;
            xsq[m]          = valid ? tsum[start + m] * (1.0f / (float)CHW) : 0.0f;
            xsq[MAXCAV + m] = valid ? tmax[start + m] : 0.0f;  // zero-pad: max=0
        }
        float h[MAXCAV];
        #pragma unroll
        for (int j = 0; j < MAXCAV; ++j) {
            float a = 0.0f;
            #pragma unroll
            for (int k = 0; k < 2 * MAXCAV; ++k) a += xsq[k] * W1[j * 2 * MAXCAV + k];
            h[j] = 1.0f / (1.0f + expf(-a));
        }
        #pragma unroll
        for (int m = 0; m < MAXCAV; ++m) {
            float g = 0.0f;
            #pragma unroll
            for (int j = 0; j < MAXCAV; ++j) g += h[j] * W2[m * MAXCAV + j];
            scoef[b][m] = conv_w[m] * fmaxf(g, 0.0f);
        }
        if (b == 0) sbias = conv_b[0];
    }
    __syncthreads();

    // ---------- phase 3: balanced apply, 528 float4 per block -------------
    const float bias  = sbias;
    const int   base3 = bid * CHUNK3;

    for (int b = 0; b < NBATCH; ++b) {
        const int len   = slen[b];
        const int start = sstart[b];
        float c[MAXCAV];
        #pragma unroll
        for (int m = 0; m < MAXCAV; ++m) c[m] = scoef[b][m];
        const int obase = b * V4;

        switch (len) {
            case 1:  apply_chunk<1>(x, c, bias, start, obase, base3, tid, out); break;
            case 2:  apply_chunk<2>(x, c, bias, start, obase, base3, tid, out); break;
            case 3:  apply_chunk<3>(x, c, bias, start, obase, base3, tid, out); break;
            case 4:  apply_chunk<4>(x, c, bias, start, obase, base3, tid, out); break;
            default: apply_chunk<5>(x, c, bias, start, obase, base3, tid, out); break;
        }
    }
}

// ======================= fallback path (R4, known-good) ====================
__global__ __launch_bounds__(256) void k_reduce(const float4* __restrict__ x,
                                                float* __restrict__ psum,
                                                float* __restrict__ pmax) {
    const int t   = blockIdx.y;
    const int blk = blockIdx.x;
    const long base = (long)t * V4 + (long)blk * V4_BLK;

    float s = 0.0f;
    float mx = -INFINITY;
    #pragma unroll 4
    for (int i = 0; i < ITERS; ++i) {
        float4 v = x[base + i * 256 + threadIdx.x];
        s += (v.x + v.y) + (v.z + v.w);
        mx = fmaxf(mx, fmaxf(fmaxf(v.x, v.y), fmaxf(v.z, v.w)));
    }

    __shared__ float ssum[256];
    __shared__ float smax[256];
    ssum[threadIdx.x] = s;
    smax[threadIdx.x] = mx;
    __syncthreads();
    #pragma unroll
    for (int off = 128; off > 0; off >>= 1) {
        if (threadIdx.x < off) {
            ssum[threadIdx.x] += ssum[threadIdx.x + off];
            smax[threadIdx.x] = fmaxf(smax[threadIdx.x], smax[threadIdx.x + off]);
        }
        __syncthreads();
    }
    if (threadIdx.x == 0) {
        psum[t * BPT + blk] = ssum[0];
        pmax[t * BPT + blk] = smax[0];
    }
}

__global__ __launch_bounds__(256) void k_gate(const float* __restrict__ psum,
                                              const float* __restrict__ pmax,
                                              const int*   __restrict__ record_len,
                                              const float* __restrict__ W1,
                                              const float* __restrict__ W2,
                                              const float* __restrict__ conv_w,
                                              int*   __restrict__ starts,
                                              float* __restrict__ coefs,
                                              int bs, int ntok) {
    __shared__ float tsum[32];
    __shared__ float tmax[32];
    const int wave = threadIdx.x >> 6;
    const int lane = threadIdx.x & 63;

    for (int t = wave; t < ntok; t += 4) {
        float s = psum[t * BPT + lane];
        float m = pmax[t * BPT + lane];
        #pragma unroll
        for (int off = 32; off > 0; off >>= 1) {
            s += __shfl_xor(s, off, 64);
            m = fmaxf(m, __shfl_xor(m, off, 64));
        }
        if (lane == 0) { tsum[t] = s; tmax[t] = m; }
    }
    __syncthreads();

    if ((int)threadIdx.x < bs) {
        const int b = threadIdx.x;
        int start = 0;
        for (int i = 0; i < b; ++i) start += record_len[i];
        const int len = record_len[b];

        float xsq[2 * MAXCAV];
        #pragma unroll
        for (int m = 0; m < MAXCAV; ++m) {
            const bool valid = m < len;
            xsq[m]          = valid ? tsum[start + m] * (1.0f / (float)CHW) : 0.0f;
            xsq[MAXCAV + m] = valid ? tmax[start + m] : 0.0f;
        }
        float h[MAXCAV];
        #pragma unroll
        for (int j = 0; j < MAXCAV; ++j) {
            float a = 0.0f;
            #pragma unroll
            for (int k = 0; k < 2 * MAXCAV; ++k) a += xsq[k] * W1[j * 2 * MAXCAV + k];
            h[j] = 1.0f / (1.0f + expf(-a));
        }
        starts[b] = start;
        #pragma unroll
        for (int m = 0; m < MAXCAV; ++m) {
            float g = 0.0f;
            #pragma unroll
            for (int j = 0; j < MAXCAV; ++j) g += h[j] * W2[m * MAXCAV + j];
            coefs[b * MAXCAV + m] = conv_w[m] * fmaxf(g, 0.0f);
        }
    }
}

template <int LEN>
__device__ __forceinline__ void fb_pair(const float4* __restrict__ x,
                                        const float* c, float bias, int start,
                                        long obase, int idx0,
                                        float4* __restrict__ out) {
    apply_idx<LEN>(x, c, bias, start, (int)obase, idx0, out);
    apply_idx<LEN>(x, c, bias, start, (int)obase, idx0 + 256, out);
}

__global__ __launch_bounds__(256) void k_apply(const float4* __restrict__ x,
                                               const int*   __restrict__ record_len,
                                               const int*   __restrict__ starts,
                                               const float* __restrict__ coefs,
                                               const float* __restrict__ conv_b,
                                               float4* __restrict__ out,
                                               int bs) {
    const int idx0 = blockIdx.x * 512 + threadIdx.x;
    const float bias = conv_b[0];

    for (int b = 0; b < bs; ++b) {
        const int len   = record_len[b];
        const int start = starts[b];
        float c[MAXCAV];
        #pragma unroll
        for (int m = 0; m < MAXCAV; ++m) c[m] = coefs[b * MAXCAV + m];
        const long obase = (long)b * V4;

        switch (len) {
            case 1:  fb_pair<1>(x, c, bias, start, obase, idx0, out); break;
            case 2:  fb_pair<2>(x, c, bias, start, obase, idx0, out); break;
            case 3:  fb_pair<3>(x, c, bias, start, obase, idx0, out); break;
            case 4:  fb_pair<4>(x, c, bias, start, obase, idx0, out); break;
            default: fb_pair<5>(x, c, bias, start, obase, idx0, out); break;
        }
    }
}

extern "C" void kernel_launch(void* const* d_in, const int* in_sizes, int n_in,
                              void* d_out, int out_size, void* d_ws, size_t ws_size,
                              hipStream_t stream) {
    const float4* x  = (const float4*)d_in[0];
    const int*    rl = (const int*)d_in[1];
    const float*  W1 = (const float*)d_in[2];
    const float*  W2 = (const float*)d_in[3];
    const float*  cw = (const float*)d_in[4];
    const float*  cb = (const float*)d_in[5];
    float4* out = (float4*)d_out;

    char* ws = (char*)d_ws;
    float* ps     = (float*)(ws);             // 2*NBLK floats = 8 KB
    float* pm     = (float*)(ws + 8192);      // 8 KB
    float* psum   = (float*)(ws + 16384);     // 25*64 floats
    float* pmax   = (float*)(ws + 16384 + 6400);
    int*   starts = (int*)  (ws + 16384 + 12800);
    float* coefs  = (float*)(ws + 16384 + 12832);

    const int ntok = in_sizes[0] / CHW;       // 25
    const int bs   = in_sizes[1];             // 8

    // Deterministic path choice: cooperative grid must be fully co-resident.
    int occ = 0;
    hipOccupancyMaxActiveBlocksPerMultiprocessor(&occ, k_fused, 256, 0);

    if (occ >= 4) {
        void* args[] = { (void*)&x, (void*)&rl, (void*)&W1, (void*)&W2,
                         (void*)&cw, (void*)&cb, (void*)&out, (void*)&ps, (void*)&pm };
        hipLaunchCooperativeKernel((void*)k_fused, dim3(NBLK), dim3(256),
                                   args, 0, stream);
    } else {
        k_reduce<<<dim3(BPT, ntok), 256, 0, stream>>>(x, psum, pmax);
        k_gate<<<1, 256, 0, stream>>>(psum, pmax, rl, W1, W2, cw, starts, coefs, bs, ntok);
        k_apply<<<V4 / 512, 256, 0, stream>>>(x, rl, starts, coefs, cb, out, bs);
    }
}

// Round 7
// 115.365 us; speedup vs baseline: 1.6382x; 1.6382x over previous
//
#include <hip/hip_runtime.h>
#include <math.h>

// SEFusion: x [N=25, C=256, H=48, W=176] f32. V4 = CHW/4 = 540,672 float4.
#define CHW     2162688
#define V4      540672
#define NTOK    25
#define NBLK    1024
#define CHUNK1  13200            // (NTOK*V4)/NBLK  -- reduce float4 per block
#define CHUNK3  528              // V4/NBLK         -- apply  float4 per block
#define MAXCAV  5
#define NBATCH  8

typedef float f32x4 __attribute__((ext_vector_type(4)));

// =================== Kernel 1: balanced reduce + last-block gate ==========
__global__ __launch_bounds__(256) void k_reduce_gate(
    const float4* __restrict__ x,
    const int*   __restrict__ record_len,
    const float* __restrict__ W1,
    const float* __restrict__ W2,
    const float* __restrict__ conv_w,
    float* __restrict__ ps,       // [2*NBLK] bucket partial sums
    float* __restrict__ pm,       // [2*NBLK] bucket partial maxes
    int*   __restrict__ counter,  // zeroed by memset each launch
    int*   __restrict__ starts,   // [NBATCH]
    float* __restrict__ coefs)    // [NBATCH*MAXCAV]
{
    const int tid  = threadIdx.x;
    const int bid  = blockIdx.x;
    const int lane = tid & 63;
    const int wave = tid >> 6;

    // ---- flat-chunk reduce, 2 token buckets per block (verified in R6) ---
    const int base  = bid * CHUNK1;
    const int t0    = base / V4;
    const int split = min((t0 + 1) * V4 - base, CHUNK1);

    float s0 = 0.f, s1 = 0.f, m0 = -INFINITY, m1 = -INFINITY;
    int li = tid;
    #pragma unroll 4
    for (; li < split; li += 256) {
        float4 v = x[base + li];
        s0 += (v.x + v.y) + (v.z + v.w);
        m0 = fmaxf(m0, fmaxf(fmaxf(v.x, v.y), fmaxf(v.z, v.w)));
    }
    #pragma unroll 4
    for (; li < CHUNK1; li += 256) {
        float4 v = x[base + li];
        s1 += (v.x + v.y) + (v.z + v.w);
        m1 = fmaxf(m1, fmaxf(fmaxf(v.x, v.y), fmaxf(v.z, v.w)));
    }
    #pragma unroll
    for (int off = 32; off > 0; off >>= 1) {
        s0 += __shfl_xor(s0, off, 64);
        s1 += __shfl_xor(s1, off, 64);
        m0 = fmaxf(m0, __shfl_xor(m0, off, 64));
        m1 = fmaxf(m1, __shfl_xor(m1, off, 64));
    }
    __shared__ float rs0[4], rs1[4], rm0[4], rm1[4];
    if (lane == 0) { rs0[wave] = s0; rs1[wave] = s1; rm0[wave] = m0; rm1[wave] = m1; }
    __syncthreads();
    if (tid == 0) {
        ps[2 * bid]     = rs0[0] + rs0[1] + rs0[2] + rs0[3];
        ps[2 * bid + 1] = rs1[0] + rs1[1] + rs1[2] + rs1[3];
        pm[2 * bid]     = fmaxf(fmaxf(rm0[0], rm0[1]), fmaxf(rm0[2], rm0[3]));
        pm[2 * bid + 1] = fmaxf(fmaxf(rm1[0], rm1[1]), fmaxf(rm1[2], rm1[3]));
    }

    // ---- last arriving block runs the gate -------------------------------
    __shared__ int is_last;
    if (tid == 0) {
        __threadfence();                       // publish ps/pm (device scope)
        is_last = (atomicAdd(counter, 1) == NBLK - 1);
    }
    __syncthreads();
    if (!is_last) return;
    __threadfence();                           // acquire all blocks' ps/pm

    __shared__ float tsum[NTOK], tmax[NTOK];
    for (int t = wave; t < NTOK; t += 4) {
        const int b_lo = (t == 0) ? 0 : ((t - 1) * V4 + CHUNK1 - 1) / CHUNK1;
        const int b_hi = min(NBLK - 1, ((t + 1) * V4 + CHUNK1 - 1) / CHUNK1 - 1);
        float s = 0.f, m = -INFINITY;
        for (int b = b_lo + lane; b <= b_hi; b += 64) {
            const int tb = (b * CHUNK1) / V4;
            if (tb == t)     { s += ps[2 * b];     m = fmaxf(m, pm[2 * b]); }
            if (tb == t - 1) { s += ps[2 * b + 1]; m = fmaxf(m, pm[2 * b + 1]); }
        }
        #pragma unroll
        for (int off = 32; off > 0; off >>= 1) {
            s += __shfl_xor(s, off, 64);
            m = fmaxf(m, __shfl_xor(m, off, 64));
        }
        if (lane == 0) { tsum[t] = s; tmax[t] = m; }
    }
    __syncthreads();

    if (tid < NBATCH) {
        const int b = tid;
        int start = 0;
        for (int i = 0; i < b; ++i) start += record_len[i];
        const int len = record_len[b];
        starts[b] = start;

        float xsq[2 * MAXCAV];
        #pragma unroll
        for (int m = 0; m < MAXCAV; ++m) {
            const bool valid = m < len;
            xsq[m]          = valid ? tsum[start + m] * (1.0f / (float)CHW) : 0.0f;
            xsq[MAXCAV + m] = valid ? tmax[start + m] : 0.0f;  // zero-pad: max=0
        }
        float h[MAXCAV];
        #pragma unroll
        for (int j = 0; j < MAXCAV; ++j) {
            float a = 0.0f;
            #pragma unroll
            for (int k = 0; k < 2 * MAXCAV; ++k) a += xsq[k] * W1[j * 2 * MAXCAV + k];
            h[j] = 1.0f / (1.0f + expf(-a));
        }
        #pragma unroll
        for (int m = 0; m < MAXCAV; ++m) {
            float g = 0.0f;
            #pragma unroll
            for (int j = 0; j < MAXCAV; ++j) g += h[j] * W2[m * MAXCAV + j];
            coefs[b * MAXCAV + m] = conv_w[m] * fmaxf(g, 0.0f);
        }
    }
}

// =================== Kernel 2: balanced apply (528 float4/block) ==========
__device__ __forceinline__ void relu_store(float ax, float ay, float az, float aw,
                                           float4* __restrict__ out, int o) {
    f32x4 acc;
    acc.x = fmaxf(ax, 0.0f);
    acc.y = fmaxf(ay, 0.0f);
    acc.z = fmaxf(az, 0.0f);
    acc.w = fmaxf(aw, 0.0f);
    __builtin_nontemporal_store(acc, (f32x4*)(out + o));
}

template <int LEN>
__device__ __forceinline__ void apply_idx(const float4* __restrict__ x,
                                          const float* c, float bias,
                                          int start, int obase, int idx,
                                          float4* __restrict__ out) {
    float ax = bias, ay = bias, az = bias, aw = bias;
    #pragma unroll
    for (int m = 0; m < LEN; ++m) {
        float4 v = x[(start + m) * V4 + idx];
        ax += c[m] * v.x;
        ay += c[m] * v.y;
        az += c[m] * v.z;
        aw += c[m] * v.w;
    }
    relu_store(ax, ay, az, aw, out, obase + idx);
}

template <int LEN>
__device__ __forceinline__ void apply_chunk(const float4* __restrict__ x,
                                            const float* c, float bias,
                                            int start, int obase, int base3,
                                            int tid, float4* __restrict__ out) {
    apply_idx<LEN>(x, c, bias, start, obase, base3 + tid, out);
    apply_idx<LEN>(x, c, bias, start, obase, base3 + 256 + tid, out);
    if (tid < CHUNK3 - 512)
        apply_idx<LEN>(x, c, bias, start, obase, base3 + 512 + tid, out);
}

__global__ __launch_bounds__(256) void k_apply(const float4* __restrict__ x,
                                               const int*   __restrict__ record_len,
                                               const int*   __restrict__ starts,
                                               const float* __restrict__ coefs,
                                               const float* __restrict__ conv_b,
                                               float4* __restrict__ out) {
    const int tid   = threadIdx.x;
    const int base3 = blockIdx.x * CHUNK3;
    const float bias = conv_b[0];

    for (int b = 0; b < NBATCH; ++b) {
        const int len   = record_len[b];
        const int start = starts[b];
        float c[MAXCAV];
        #pragma unroll
        for (int m = 0; m < MAXCAV; ++m) c[m] = coefs[b * MAXCAV + m];
        const int obase = b * V4;

        switch (len) {
            case 1:  apply_chunk<1>(x, c, bias, start, obase, base3, tid, out); break;
            case 2:  apply_chunk<2>(x, c, bias, start, obase, base3, tid, out); break;
            case 3:  apply_chunk<3>(x, c, bias, start, obase, base3, tid, out); break;
            case 4:  apply_chunk<4>(x, c, bias, start, obase, base3, tid, out); break;
            default: apply_chunk<5>(x, c, bias, start, obase, base3, tid, out); break;
        }
    }
}

extern "C" void kernel_launch(void* const* d_in, const int* in_sizes, int n_in,
                              void* d_out, int out_size, void* d_ws, size_t ws_size,
                              hipStream_t stream) {
    const float4* x  = (const float4*)d_in[0];
    const int*    rl = (const int*)d_in[1];
    const float*  W1 = (const float*)d_in[2];
    const float*  W2 = (const float*)d_in[3];
    const float*  cw = (const float*)d_in[4];
    const float*  cb = (const float*)d_in[5];
    float4* out = (float4*)d_out;

    char* ws = (char*)d_ws;
    int*   counter = (int*)  (ws);             // 4 B (+60 pad)
    float* ps      = (float*)(ws + 64);        // 2*NBLK floats = 8 KB
    float* pm      = (float*)(ws + 64 + 8192); // 8 KB
    int*   starts  = (int*)  (ws + 64 + 16384);
    float* coefs   = (float*)(ws + 64 + 16384 + 64);

    hipMemsetAsync(counter, 0, sizeof(int), stream);
    k_reduce_gate<<<NBLK, 256, 0, stream>>>(x, rl, W1, W2, cw,
                                            ps, pm, counter, starts, coefs);
    k_apply<<<NBLK, 256, 0, stream>>>(x, rl, starts, coefs, cb, out);
}